// Round 1
// baseline (184.064 us; speedup 1.0000x reference)
//
#include <hip/hip_runtime.h>
#include <math.h>

#define NENT 50000
#define NREL 500
#define DIMK 128
#define BATCH 32

// ws layout (floats): [0 .. 8191] predRI interleaved: (b*128+d)*2 + {re,im}
//                     [8192 .. 8223] pred_r_sum[b]
#define WS_PRED_FLOATS (BATCH * DIMK * 2)

__device__ __forceinline__ float softplus_f(float x) {
    // stable: max(x,0) + log(1 + exp(-|x|)); values here are tiny so log(1+t) is fine
    float e = __expf(-fabsf(x));
    return fmaxf(x, 0.0f) + __logf(1.0f + e);
}

__device__ __forceinline__ float fast_sqrtf(float x) {
#if __has_builtin(__builtin_amdgcn_sqrtf)
    return __builtin_amdgcn_sqrtf(x);   // v_sqrt_f32, ~1 ulp
#else
    return sqrtf(x);
#endif
}

// Robustly fetch triplet index whether the buffer is int32 or int64.
// int64-actual: all 48 first i64 views are in [0,500). int32-actual: i64 views
// combine two indices -> >= 2^32 somewhere. Only reads 48*8 = 384 B (safe both ways).
__device__ __forceinline__ int get_idx(const void* trip, int flat) {
    const long long* t64 = (const long long*)trip;
    const int* t32 = (const int*)trip;
    bool is64 = true;
    #pragma unroll 1
    for (int i = 0; i < 48; ++i) {
        long long v = t64[i];
        if (v < 0 || v >= NREL) { is64 = false; break; }
    }
    return is64 ? (int)t64[flat] : t32[flat];
}

__global__ __launch_bounds__(128)
void prep_kernel(const float* __restrict__ ent_center,
                 const float* __restrict__ ent_rho,
                 const float* __restrict__ rel_center,
                 const float* __restrict__ rel_rho,
                 const void* __restrict__ trip,
                 float* __restrict__ ws) {
    const int b = blockIdx.x;      // 0..31
    const int d = threadIdx.x;     // 0..127
    const int h = get_idx(trip, b * 3 + 0);
    const int r = get_idx(trip, b * 3 + 1);

    float hre = ent_center[h * 256 + d];
    float him = ent_center[h * 256 + 128 + d];
    float ph  = rel_center[r * 128 + d];
    float s = sinf(ph), c = cosf(ph);          // precise; only 4096 lanes total
    float pre = hre * c - him * s;
    float pim = hre * s + him * c;
    ws[(b * 128 + d) * 2 + 0] = pre;
    ws[(b * 128 + d) * 2 + 1] = pim;

    float pr = softplus_f(ent_rho[h * 128 + d]) + softplus_f(rel_rho[r * 128 + d]);
    #pragma unroll
    for (int off = 32; off > 0; off >>= 1) pr += __shfl_down(pr, off);
    __shared__ float tmp[2];
    if ((threadIdx.x & 63) == 0) tmp[threadIdx.x >> 6] = pr;
    __syncthreads();
    if (threadIdx.x == 0) ws[WS_PRED_FLOATS + b] = tmp[0] + tmp[1];
}

// Block: 256 threads = 4 waves. lane -> entity (64 per block), wave -> 32-dim slice.
// acc[BATCH] per thread in registers; cross-wave combine via padded LDS.
__global__ __launch_bounds__(256, 2)
void score_kernel(const float* __restrict__ ent_center,
                  const float* __restrict__ ent_rho,
                  const float* __restrict__ ws,
                  float* __restrict__ out) {
    __shared__ float s_pred[WS_PRED_FLOATS];   // 32 KB
    __shared__ float s_psum[BATCH];
    __shared__ float s_red[3 * 64 * 33];       // 25.3 KB, +33 pad -> 2-way bank alias (free)

    const int tid = threadIdx.x;
    {   // stage pred tile: 2048 float4 / 256 threads = 8 each (coalesced)
        const float4* wsv = (const float4*)ws;
        float4* sp4 = (float4*)s_pred;
        #pragma unroll
        for (int i = 0; i < 8; ++i) sp4[tid + 256 * i] = wsv[tid + 256 * i];
        if (tid < BATCH) s_psum[tid] = ws[WS_PRED_FLOATS + tid];
    }
    __syncthreads();

    const int wave = tid >> 6, lane = tid & 63;
    const int e = blockIdx.x * 64 + lane;
    const int ec = (e < NENT) ? e : (NENT - 1);        // clamp OOB lanes' loads
    const float4* cen = (const float4*)(ent_center + (size_t)ec * 256);
    const float4* rho = (const float4*)(ent_rho + (size_t)ec * 128);
    const int qbase = wave * 8;                        // float4 index of this wave's dim slice

    float acc[BATCH];
    #pragma unroll
    for (int b = 0; b < BATCH; ++b) acc[b] = 0.0f;
    float ursum = 0.0f;

    #pragma unroll 1
    for (int dc = 0; dc < 8; ++dc) {
        const int dq = qbase + dc;                     // dims 4*dq .. 4*dq+3
        float4 ur = cen[dq];                           // u_re
        float4 ui = cen[32 + dq];                      // u_im
        float4 rr = rho[dq];
        ursum += softplus_f(rr.x) + softplus_f(rr.y) + softplus_f(rr.z) + softplus_f(rr.w);

        const float* pbase = s_pred + dq * 8;
        #pragma unroll
        for (int b = 0; b < BATCH; ++b) {
            const float4* p = (const float4*)(pbase + b * 256);  // broadcast reads
            float4 p01 = p[0];                         // re0,im0,re1,im1
            float4 p23 = p[1];                         // re2,im2,re3,im3
            float dre, dim_, t;
            dre = p01.x - ur.x; dim_ = p01.y - ui.x; t = dre * dre + dim_ * dim_; acc[b] += fast_sqrtf(t);
            dre = p01.z - ur.y; dim_ = p01.w - ui.y; t = dre * dre + dim_ * dim_; acc[b] += fast_sqrtf(t);
            dre = p23.x - ur.z; dim_ = p23.y - ui.z; t = dre * dre + dim_ * dim_; acc[b] += fast_sqrtf(t);
            dre = p23.z - ur.w; dim_ = p23.w - ui.w; t = dre * dre + dim_ * dim_; acc[b] += fast_sqrtf(t);
        }
    }

    if (wave > 0) {
        float* rp = s_red + ((wave - 1) * 64 + lane) * 33;
        #pragma unroll
        for (int b = 0; b < BATCH; ++b) rp[b] = acc[b];
        rp[32] = ursum;
    }
    __syncthreads();

    if (wave == 0 && e < NENT) {
        #pragma unroll
        for (int k = 0; k < 3; ++k) {
            const float* rp = s_red + (k * 64 + lane) * 33;
            #pragma unroll
            for (int b = 0; b < BATCH; ++b) acc[b] += rp[b];
            ursum += rp[32];
        }
        #pragma unroll
        for (int b = 0; b < BATCH; ++b)
            out[(size_t)b * NENT + e] = s_psum[b] + ursum - acc[b];
    }
}

extern "C" void kernel_launch(void* const* d_in, const int* in_sizes, int n_in,
                              void* d_out, int out_size, void* d_ws, size_t ws_size,
                              hipStream_t stream) {
    const float* ent_center = (const float*)d_in[0];
    const float* ent_rho    = (const float*)d_in[1];
    const float* rel_center = (const float*)d_in[2];
    const float* rel_rho    = (const float*)d_in[3];
    const void*  trip       = d_in[4];
    float* ws  = (float*)d_ws;
    float* out = (float*)d_out;

    prep_kernel<<<BATCH, 128, 0, stream>>>(ent_center, ent_rho, rel_center, rel_rho, trip, ws);
    score_kernel<<<(NENT + 63) / 64, 256, 0, stream>>>(ent_center, ent_rho, ws, out);
}

// Round 2
// 160.110 us; speedup vs baseline: 1.1496x; 1.1496x over previous
//
#include <hip/hip_runtime.h>
#include <math.h>

#define NENT 50000
#define NREL 500
#define DIMK 128
#define BATCH 32

// ws layout (floats):
//   [0 .. 8191]      pred re/im interleaved: (b*128+d)*2 + {0:re,1:im}
//   [8192 .. 8223]   pred_r_sum[b]
//   [8224 .. 58223]  u_r_sum[e]  (softplus(ent_rho).sum per entity)
#define WS_PRED 0
#define WS_PSUM 8192
#define WS_URSUM 8224

__device__ __forceinline__ float softplus_f(float x) {
    float e = __expf(-fabsf(x));
    return fmaxf(x, 0.0f) + __logf(1.0f + e);
}

__device__ __forceinline__ float fast_sqrtf(float x) {
#if __has_builtin(__builtin_amdgcn_sqrtf)
    return __builtin_amdgcn_sqrtf(x);
#else
    return sqrtf(x);
#endif
}

// Robust triplet index fetch (int32 or int64 buffer).
__device__ __forceinline__ int get_idx(const void* trip, int flat) {
    const long long* t64 = (const long long*)trip;
    const int* t32 = (const int*)trip;
    bool is64 = true;
    #pragma unroll 1
    for (int i = 0; i < 48; ++i) {
        long long v = t64[i];
        if (v < 0 || v >= NREL) { is64 = false; break; }
    }
    return is64 ? (int)t64[flat] : t32[flat];
}

__global__ __launch_bounds__(128)
void prep_kernel(const float* __restrict__ ent_center,
                 const float* __restrict__ ent_rho,
                 const float* __restrict__ rel_center,
                 const float* __restrict__ rel_rho,
                 const void* __restrict__ trip,
                 float* __restrict__ ws) {
    const int b = blockIdx.x;      // 0..31
    const int d = threadIdx.x;     // 0..127
    const int h = get_idx(trip, b * 3 + 0);
    const int r = get_idx(trip, b * 3 + 1);

    float hre = ent_center[h * 256 + d];
    float him = ent_center[h * 256 + 128 + d];
    float ph  = rel_center[r * 128 + d];
    float s = sinf(ph), c = cosf(ph);
    ws[WS_PRED + (b * 128 + d) * 2 + 0] = hre * c - him * s;
    ws[WS_PRED + (b * 128 + d) * 2 + 1] = hre * s + him * c;

    float pr = softplus_f(ent_rho[h * 128 + d]) + softplus_f(rel_rho[r * 128 + d]);
    #pragma unroll
    for (int off = 32; off > 0; off >>= 1) pr += __shfl_down(pr, off);
    __shared__ float tmp[2];
    if ((threadIdx.x & 63) == 0) tmp[threadIdx.x >> 6] = pr;
    __syncthreads();
    if (threadIdx.x == 0) ws[WS_PSUM + b] = tmp[0] + tmp[1];
}

// u_r_sum pre-pass: one wave per entity, coalesced float2 row read.
__global__ __launch_bounds__(256)
void ursum_kernel(const float* __restrict__ ent_rho, float* __restrict__ ws) {
    const int wave = threadIdx.x >> 6, lane = threadIdx.x & 63;
    const int e = blockIdx.x * 4 + wave;
    if (e >= NENT) return;
    float2 v = *(const float2*)(ent_rho + (size_t)e * 128 + lane * 2);
    float s = softplus_f(v.x) + softplus_f(v.y);
    #pragma unroll
    for (int off = 32; off > 0; off >>= 1) s += __shfl_down(s, off);
    if (lane == 0) ws[WS_URSUM + e] = s;
}

// Block: 256 threads = 4 waves, 64 entities (lane -> entity).
// Wave w owns batches [8w, 8w+8), all 128 dims. No cross-wave reduction.
// Entity center staged per 32-dim chunk in LDS, full-128B-line coalesced
// global loads + XOR-swizzled transpose (conflict-free write AND read).
__global__ __launch_bounds__(256, 3)
void score_kernel(const float* __restrict__ ent_center,
                  const float* __restrict__ ws,
                  float* __restrict__ out) {
    __shared__ float4 s_pred[2048];    // 32 KB, fl4 idx = b*64 + d/2 (interleaved re/im)
    __shared__ float4 s_stage[1024];   // 16 KB: slot = (s*8+q)*64 + (et ^ q)

    const int tid = threadIdx.x;
    const int wave = tid >> 6, lane = tid & 63;
    const int e0 = blockIdx.x * 64;
    const int q = tid & 7;          // fl4-within-line index for staging loads
    const int et0 = tid >> 3;       // 0..31, entity-within-block (+32 on round 1)
    const float4* cen4 = (const float4*)ent_center;
    const float4* ws4 = (const float4*)ws;

    // stage pred tile (2048 fl4 / 256 thr = 8 each, coalesced)
    #pragma unroll
    for (int i = 0; i < 8; ++i) s_pred[tid + 256 * i] = ws4[tid + 256 * i];

    float4 g[4];
    auto GLOAD = [&](int c) {
        #pragma unroll
        for (int s = 0; s < 2; ++s)
            #pragma unroll
            for (int r = 0; r < 2; ++r) {
                int ge = e0 + et0 + 32 * r;
                if (ge > NENT - 1) ge = NENT - 1;
                g[s * 2 + r] = cen4[(size_t)ge * 64 + s * 32 + c * 8 + q];
            }
    };
    auto DSWRITE = [&]() {
        #pragma unroll
        for (int s = 0; s < 2; ++s)
            #pragma unroll
            for (int r = 0; r < 2; ++r) {
                int et = et0 + 32 * r;
                s_stage[(s * 8 + q) * 64 + (et ^ q)] = g[s * 2 + r];
            }
    };

    float acc[8];
    #pragma unroll
    for (int b = 0; b < 8; ++b) acc[b] = 0.0f;

    GLOAD(0);
    __syncthreads();                       // pred tile visible
    #pragma unroll 1
    for (int c = 0; c < 4; ++c) {
        if (c) __syncthreads();            // all waves done reading previous chunk
        DSWRITE();                         // (vmcnt auto-wait on g)
        if (c < 3) GLOAD(c + 1);           // issue next chunk early, consumed next iter
        __syncthreads();                   // stage visible
        #pragma unroll
        for (int dq = 0; dq < 8; ++dq) {
            const float4 ur = s_stage[dq * 64 + (lane ^ dq)];
            const float4 ui = s_stage[(8 + dq) * 64 + (lane ^ dq)];
            #pragma unroll
            for (int bb = 0; bb < 8; ++bb) {
                const int b = wave * 8 + bb;
                const int p0 = b * 64 + c * 16 + dq * 2;
                const float4 p01 = s_pred[p0];       // broadcast (free)
                const float4 p23 = s_pred[p0 + 1];
                float dre, dmi, t;
                dre = p01.x - ur.x; dmi = p01.y - ui.x; t = dre * dre + dmi * dmi; acc[bb] += fast_sqrtf(t);
                dre = p01.z - ur.y; dmi = p01.w - ui.y; t = dre * dre + dmi * dmi; acc[bb] += fast_sqrtf(t);
                dre = p23.x - ur.z; dmi = p23.y - ui.z; t = dre * dre + dmi * dmi; acc[bb] += fast_sqrtf(t);
                dre = p23.z - ur.w; dmi = p23.w - ui.w; t = dre * dre + dmi * dmi; acc[bb] += fast_sqrtf(t);
            }
        }
    }

    const int e = e0 + lane;
    if (e < NENT) {
        const float ursum = ws[WS_URSUM + e];
        #pragma unroll
        for (int bb = 0; bb < 8; ++bb) {
            const int b = wave * 8 + bb;
            out[(size_t)b * NENT + e] = ws[WS_PSUM + b] + ursum - acc[bb];
        }
    }
}

extern "C" void kernel_launch(void* const* d_in, const int* in_sizes, int n_in,
                              void* d_out, int out_size, void* d_ws, size_t ws_size,
                              hipStream_t stream) {
    const float* ent_center = (const float*)d_in[0];
    const float* ent_rho    = (const float*)d_in[1];
    const float* rel_center = (const float*)d_in[2];
    const float* rel_rho    = (const float*)d_in[3];
    const void*  trip       = d_in[4];
    float* ws  = (float*)d_ws;
    float* out = (float*)d_out;

    ursum_kernel<<<(NENT + 3) / 4, 256, 0, stream>>>(ent_rho, ws);
    prep_kernel<<<BATCH, 128, 0, stream>>>(ent_center, ent_rho, rel_center, rel_rho, trip, ws);
    score_kernel<<<(NENT + 63) / 64, 256, 0, stream>>>(ent_center, ws, out);
}